// Round 4
// baseline (316.476 us; speedup 1.0000x reference)
//
#include <hip/hip_runtime.h>
#include <hip/hip_bf16.h>

#define ALPHA_ 1.0f
#define BETA_  0.5f
#define GAMMA_ 0.3f
#define EPS_   1e-8f

typedef unsigned short u16;
typedef unsigned int u32;

constexpr int B_ = 32, C_ = 256, F_ = 2048;
constexpr int NTOT = B_ * C_ * F_;          // 16777216
constexpr int G8   = NTOT / 8;              // 2097152 groups of 8 elems
constexpr int NCC  = B_ * C_ * C_;          // 2097152

typedef __bf16 bf16x8 __attribute__((ext_vector_type(8)));
typedef float  f32x4  __attribute__((ext_vector_type(4)));

// round-to-nearest-even float -> bf16 bits (sin/cos inputs, no NaN/Inf)
__device__ __forceinline__ u32 f2bf(float x) {
    unsigned u = __float_as_uint(x);
    u += 0x7fffu + ((u >> 16) & 1u);
    return (u >> 16);
}

// async global->LDS, 16 B per lane; LDS dst = wave-uniform base + lane*16
__device__ __forceinline__ void async_copy16(const void* g, void* l) {
    __builtin_amdgcn_global_load_lds(
        (const __attribute__((address_space(1))) unsigned int*)g,
        (__attribute__((address_space(3))) unsigned int*)l,
        16, 0, 0);
}

// ---------------------------------------------------------------------------
// Kernel A1: mag MSE — pure 2-stream read-reduce (128 MB)
// ---------------------------------------------------------------------------
__global__ void __launch_bounds__(256)
mag_kernel(const float4* __restrict__ mh, const float4* __restrict__ mt,
           float* __restrict__ accum)
{
    __shared__ float sm[4];
    const int tid    = blockIdx.x * 256 + threadIdx.x;
    const int stride = 4096 * 256;          // 1048576; G8/stride = 2
    float msum = 0.f;

    #pragma unroll
    for (int it = 0; it < 2; ++it) {
        int g = tid + it * stride;
        float4 a0 = mh[2*g], a1 = mh[2*g+1];
        float4 b0 = mt[2*g], b1 = mt[2*g+1];
        float d0 = a0.x-b0.x, d1 = a0.y-b0.y, d2 = a0.z-b0.z, d3 = a0.w-b0.w;
        float d4 = a1.x-b1.x, d5 = a1.y-b1.y, d6 = a1.z-b1.z, d7 = a1.w-b1.w;
        msum += d0*d0 + d1*d1 + d2*d2 + d3*d3 + d4*d4 + d5*d5 + d6*d6 + d7*d7;
    }

    #pragma unroll
    for (int o = 32; o > 0; o >>= 1) msum += __shfl_down(msum, o, 64);
    int lane = threadIdx.x & 63, wv = threadIdx.x >> 6;
    if (lane == 0) sm[wv] = msum;
    __syncthreads();
    if (threadIdx.x == 0) atomicAdd(&accum[0], sm[0] + sm[1] + sm[2] + sm[3]);
}

// ---------------------------------------------------------------------------
// Kernel A2: phase loss + cos/sin(phase_hat) as bf16 (128 MB read, 64 MB write)
// ---------------------------------------------------------------------------
__global__ void __launch_bounds__(256)
phase_kernel(const float4* __restrict__ ph, const float4* __restrict__ pt,
             int4* __restrict__ cb4, int4* __restrict__ sb4,
             float* __restrict__ accum)
{
    __shared__ float sp[4];
    const int tid    = blockIdx.x * 256 + threadIdx.x;
    const int stride = 4096 * 256;          // 1048576; G8/stride = 2
    float psum = 0.f;

    #pragma unroll
    for (int it = 0; it < 2; ++it) {
        int g = tid + it * stride;
        float4 p0 = ph[2*g], p1 = ph[2*g+1];
        float4 q0 = pt[2*g], q1 = pt[2*g+1];
        float pv[8] = {p0.x, p0.y, p0.z, p0.w, p1.x, p1.y, p1.z, p1.w};
        float qv[8] = {q0.x, q0.y, q0.z, q0.w, q1.x, q1.y, q1.z, q1.w};
        u32 cu[8], su[8];
        #pragma unroll
        for (int j = 0; j < 8; j++) {
            psum += 1.f - __cosf(pv[j] - qv[j]);
            float s, c;
            __sincosf(pv[j], &s, &c);
            cu[j] = f2bf(c);
            su[j] = f2bf(s);
        }
        cb4[g] = make_int4((int)(cu[0] | (cu[1] << 16)), (int)(cu[2] | (cu[3] << 16)),
                           (int)(cu[4] | (cu[5] << 16)), (int)(cu[6] | (cu[7] << 16)));
        sb4[g] = make_int4((int)(su[0] | (su[1] << 16)), (int)(su[2] | (su[3] << 16)),
                           (int)(su[4] | (su[5] << 16)), (int)(su[6] | (su[7] << 16)));
    }

    #pragma unroll
    for (int o = 32; o > 0; o >>= 1) psum += __shfl_down(psum, o, 64);
    int lane = threadIdx.x & 63, wv = threadIdx.x >> 6;
    if (lane == 0) sp[wv] = psum;
    __syncthreads();
    if (threadIdx.x == 0) atomicAdd(&accum[1], sp[0] + sp[1] + sp[2] + sp[3]);
}

// ---------------------------------------------------------------------------
// Kernel B: batched MFMA -> pci -> (pci-target)^2 reduce, SYMMETRIC version.
// p = sqrt(re^2+im^2) is symmetric in (i,j): compute only the 10 upper
// 64x64 tiles per batch; off-diagonal tiles contribute both (p-t[i][j])^2
// and (p-t[j][i])^2. Diagonal tiles stage one slab (A==B) and predicate
// per element (j>i: both, j==i: one, j<i: none).
// Staging via global_load_lds (16B) with XOR swizzle (round-3 verified).
// ---------------------------------------------------------------------------
__global__ void __launch_bounds__(256)
pci_kernel(const u16* __restrict__ cb, const u16* __restrict__ sb,
           const float* __restrict__ tgt, float* __restrict__ accum)
{
    __shared__ char lds[32768];          // A tile 16 KB | B tile 16 KB
    __shared__ float sred[4];
    char* la = lds;
    char* lb = lds + 16384;

    // 320 blocks: XCD x = g&7 hosts batches 4x..4x+3 (40 jobs each)
    const int g  = blockIdx.x;
    const int x  = g & 7, sq = g >> 3;           // sq in [0,40)
    const int y  = (x << 2) | (sq & 3);          // batch
    const int job = sq >> 2;                     // 0..9 upper-tri tile
    int ti, tj;
    if      (job < 4) { ti = 0; tj = job; }
    else if (job < 7) { ti = 1; tj = job - 3; }
    else if (job < 9) { ti = 2; tj = job - 5; }
    else              { ti = 3; tj = 3; }
    const bool diag = (ti == tj);
    const int i0 = ti * 64, j0 = tj * 64;

    const int t    = threadIdx.x;
    const int lane = t & 63, w = t >> 6;
    const int wrow = (w >> 1) * 32, wcol = (w & 1) * 32;
    const int m = lane & 15, q = lane >> 4;

    // staging source pointers (XOR swizzle folded into global address)
    const char* gA[4];
    const char* gB[4];
    {
        const int p = lane & 15;
        #pragma unroll
        for (int r = 0; r < 4; ++r) {
            int row = w * 16 + r * 4 + (lane >> 4);
            int c   = p ^ (row & 15);            // logical chunk
            const u16* arr = (c < 8) ? cb : sb;  // cos | sin stream
            int cc = c & 7;
            gA[r] = (const char*)arr + ((size_t)(y * 256 + i0 + row)) * 4096 + cc * 16;
            gB[r] = (const char*)arr + ((size_t)(y * 256 + j0 + row)) * 4096 + cc * 16;
        }
    }
    char* lbp = diag ? la : lb;       // B-fragment source

    f32x4 zero = {0.f, 0.f, 0.f, 0.f};
    f32x4 accR[2][2], accSC[2][2], accCS[2][2];
    #pragma unroll
    for (int a = 0; a < 2; a++)
        #pragma unroll
        for (int c = 0; c < 2; c++) {
            accR[a][c] = zero; accSC[a][c] = zero; accCS[a][c] = zero;
        }

    for (int it = 0; it < 32; ++it) {
        __syncthreads();
        #pragma unroll
        for (int r = 0; r < 4; ++r) {
            async_copy16(gA[r], la + w * 4096 + r * 1024);
            gA[r] += 128;
        }
        if (!diag) {
            #pragma unroll
            for (int r = 0; r < 4; ++r) {
                async_copy16(gB[r], lb + w * 4096 + r * 1024);
                gB[r] += 128;
            }
        }
        __syncthreads();

        #pragma unroll
        for (int s = 0; s < 2; ++s) {
            bf16x8 fac[2], fas[2], fbc[2], fbs[2];
            #pragma unroll
            for (int a = 0; a < 2; a++) {
                const char* base = la + (wrow + a * 16 + m) * 256;
                int pc = ((4 * s + q) ^ m) * 16;
                fac[a] = *(const bf16x8*)(base + pc);
                fas[a] = *(const bf16x8*)(base + (pc ^ 128));
            }
            #pragma unroll
            for (int c = 0; c < 2; c++) {
                const char* base = lbp + (wcol + c * 16 + m) * 256;
                int pc = ((4 * s + q) ^ m) * 16;
                fbc[c] = *(const bf16x8*)(base + pc);
                fbs[c] = *(const bf16x8*)(base + (pc ^ 128));
            }
            #pragma unroll
            for (int a = 0; a < 2; a++)
                #pragma unroll
                for (int c = 0; c < 2; c++) {
                    accR[a][c]  = __builtin_amdgcn_mfma_f32_16x16x32_bf16(fac[a], fbc[c], accR[a][c], 0, 0, 0);
                    accR[a][c]  = __builtin_amdgcn_mfma_f32_16x16x32_bf16(fas[a], fbs[c], accR[a][c], 0, 0, 0);
                    accSC[a][c] = __builtin_amdgcn_mfma_f32_16x16x32_bf16(fas[a], fbc[c], accSC[a][c], 0, 0, 0);
                    accCS[a][c] = __builtin_amdgcn_mfma_f32_16x16x32_bf16(fac[a], fbs[c], accCS[a][c], 0, 0, 0);
                }
        }
    }

    // epilogue: symmetric squared-error accumulation
    const float inv_f = 1.0f / (float)F_;
    float coh = 0.f;
    const float* tb = tgt + (size_t)y * (C_ * C_);
    #pragma unroll
    for (int a = 0; a < 2; a++)
        #pragma unroll
        for (int c = 0; c < 2; c++) {
            int ir0  = i0 + wrow + a * 16 + q * 4;   // C/D: row=(lane>>4)*4+reg
            int jcol = j0 + wcol + c * 16 + m;       // C/D: col=lane&15
            #pragma unroll
            for (int r = 0; r < 4; r++) {
                int irow = ir0 + r;
                float re = accR[a][c][r] * inv_f;
                float im = (accSC[a][c][r] - accCS[a][c][r]) * inv_f;
                float p  = sqrtf(re * re + im * im + EPS_);
                float d1 = p - tb[irow * C_ + jcol];
                float d2 = p - tb[jcol * C_ + irow];
                if (diag) {
                    if (jcol > irow)       coh += d1 * d1 + d2 * d2;
                    else if (jcol == irow) coh += d1 * d1;
                } else {
                    coh += d1 * d1 + d2 * d2;
                }
            }
        }

    #pragma unroll
    for (int o = 32; o > 0; o >>= 1) coh += __shfl_down(coh, o, 64);
    if (lane == 0) sred[w] = coh;
    __syncthreads();
    if (t == 0) atomicAdd(&accum[2], sred[0] + sred[1] + sred[2] + sred[3]);
}

// ---------------------------------------------------------------------------
// Kernel C: finalize the 4 scalars
// ---------------------------------------------------------------------------
__global__ void fin_kernel(const float* __restrict__ accum, float* __restrict__ out)
{
    if (threadIdx.x == 0) {
        float mag = accum[0] * (1.0f / (float)NTOT);
        float phs = accum[1] * (1.0f / (float)NTOT);
        float coh = accum[2] * (1.0f / (float)NCC);
        out[0] = ALPHA_ * mag + BETA_ * phs + GAMMA_ * coh;
        out[1] = mag;
        out[2] = phs;
        out[3] = coh;
    }
}

extern "C" void kernel_launch(void* const* d_in, const int* in_sizes, int n_in,
                              void* d_out, int out_size, void* d_ws, size_t ws_size,
                              hipStream_t stream)
{
    const float* mh  = (const float*)d_in[0];
    const float* ph  = (const float*)d_in[1];
    const float* mt  = (const float*)d_in[2];
    const float* pt  = (const float*)d_in[3];
    const float* tgt = (const float*)d_in[4];
    float* out = (float*)d_out;

    // ws layout: [0..3] float accumulators | cb (32 MB) | sb (32 MB)
    float* accum = (float*)d_ws;
    u16* cb = (u16*)((char*)d_ws + 256);
    u16* sb = cb + (size_t)NTOT;

    hipMemsetAsync(d_ws, 0, 16, stream);

    mag_kernel<<<4096, 256, 0, stream>>>(
        (const float4*)mh, (const float4*)mt, accum);

    phase_kernel<<<4096, 256, 0, stream>>>(
        (const float4*)ph, (const float4*)pt, (int4*)cb, (int4*)sb, accum);

    pci_kernel<<<320, 256, 0, stream>>>(cb, sb, tgt, accum);

    fin_kernel<<<1, 64, 0, stream>>>(accum, out);
}